// Round 7
// baseline (982.734 us; speedup 1.0000x reference)
//
#include <hip/hip_runtime.h>
#include <math.h>

#define NN 50000
#define EN 200000
#define CC 4
#define HH 128
#define GG 64
#define LDSA 136  // bf16 row stride (+8 pad keeps 16B alignment, rotates bank groups)
#define LDSF 132  // f32 row stride for fused-pool tile

typedef __attribute__((ext_vector_type(8))) short bs8;
typedef __attribute__((ext_vector_type(4))) float f32x4;

__device__ __forceinline__ unsigned short f2bf(float f) {
  unsigned int u = __float_as_uint(f);
  u += 0x7FFFu + ((u >> 16) & 1u);
  return (unsigned short)(u >> 16);
}
__device__ __forceinline__ float bf2f(unsigned short h) {
  return __uint_as_float(((unsigned int)h) << 16);
}
// fast erf-GELU: A&S 7.1.26 minimax (|erf err| ~1.5e-7) + hw rcp/exp
__device__ __forceinline__ float gelu_f(float x) {
  float z = fabsf(x) * 0.7071067811865476f;
  float t = __builtin_amdgcn_rcpf(fmaf(0.3275911f, z, 1.0f));
  float poly = t * fmaf(t, fmaf(t, fmaf(t, fmaf(t, 1.061405429f, -1.453152027f),
                                        1.421413741f), -0.284496736f), 0.254829592f);
  float e = fmaf(-poly, __expf(-z * z), 1.0f);
  return 0.5f * x * (1.0f + copysignf(e, x));
}

// ---------------- CSR build ----------------
__global__ __launch_bounds__(256) void count_kernel(const int* __restrict__ dst,
                                                    int* __restrict__ counts) {
  int e = blockIdx.x * 256 + threadIdx.x;
  if (e < EN) atomicAdd(&counts[dst[e]], 1);
}

__global__ __launch_bounds__(256) void block_sum_kernel(const int* __restrict__ counts,
                                                        int* __restrict__ bsums) {
  int tid = threadIdx.x;
  int i = blockIdx.x * 256 + tid;
  int v = (i < NN) ? counts[i] : 0;
#pragma unroll
  for (int d = 1; d < 64; d <<= 1) v += __shfl_xor(v, d);
  __shared__ int ws4[4];
  if ((tid & 63) == 0) ws4[tid >> 6] = v;
  __syncthreads();
  if (tid == 0) bsums[blockIdx.x] = ws4[0] + ws4[1] + ws4[2] + ws4[3];
}

__global__ __launch_bounds__(256) void bsum_scan_kernel(const int* __restrict__ bsums,
                                                        int* __restrict__ boffs, int nb) {
  int tid = threadIdx.x, lane = tid & 63, wv = tid >> 6;
  int v = (tid < nb) ? bsums[tid] : 0;
  int s = v;
#pragma unroll
  for (int d = 1; d < 64; d <<= 1) { int t = __shfl_up(s, d); if (lane >= d) s += t; }
  __shared__ int wsum[4];
  if (lane == 63) wsum[wv] = s;
  __syncthreads();
  int pre = 0;
  for (int j = 0; j < wv; ++j) pre += wsum[j];
  if (tid < nb) boffs[tid] = pre + s - v;
}

__global__ __launch_bounds__(256) void block_scan_kernel(const int* __restrict__ counts,
                                                         const int* __restrict__ boffs,
                                                         int* __restrict__ offsets,
                                                         int* __restrict__ cursor) {
  int tid = threadIdx.x, lane = tid & 63, wv = tid >> 6;
  int i = blockIdx.x * 256 + tid;
  int v = (i < NN) ? counts[i] : 0;
  int s = v;
#pragma unroll
  for (int d = 1; d < 64; d <<= 1) { int t = __shfl_up(s, d); if (lane >= d) s += t; }
  __shared__ int wsum[4];
  if (lane == 63) wsum[wv] = s;
  __syncthreads();
  int pre = boffs[blockIdx.x];
  for (int j = 0; j < wv; ++j) pre += wsum[j];
  if (i < NN) { int e = pre + s - v; offsets[i] = e; cursor[i] = e; }
  if (i == 0) offsets[NN] = EN;
}

__global__ __launch_bounds__(256) void fill_kernel(const int* __restrict__ dst,
                                                   int* __restrict__ cursor,
                                                   int* __restrict__ csr_e) {
  int e = blockIdx.x * 256 + threadIdx.x;
  if (e < EN) {
    int pos = atomicAdd(&cursor[dst[e]], 1);
    csr_e[pos] = e;
  }
}

// ---------------- weight prep: transpose + hi/lo bf16 split (all 6 matrices) ------
__global__ __launch_bounds__(256) void prep_w_kernel(const float* __restrict__ W1,
                                                     const float* __restrict__ W2,
                                                     const float* __restrict__ Wm1,
                                                     const float* __restrict__ Wm2,
                                                     unsigned short* __restrict__ wts) {
  int m = blockIdx.x >> 6;
  int idx = (blockIdx.x & 63) * 256 + threadIdx.x;  // 0..16383
  const float* src = (m == 0) ? W1 : (m == 1) ? W1 + 16384 : (m == 2) ? W2
                     : (m == 3) ? W2 + 16384 : (m == 4) ? Wm1 : Wm2;
  unsigned short* dhi = wts + m * 32768;
  unsigned short* dlo = dhi + 16384;
  int n = idx >> 7, k = idx & 127;
  float v = src[k * HH + n];  // src [k][n] -> dst [n][k]
  unsigned short hi = f2bf(v);
  dhi[n * HH + k] = hi;
  dlo[n * HH + k] = f2bf(v - bf2f(hi));
}

// ---------------- bond encoder: 16 edges per block ----------------
__global__ __launch_bounds__(256) void ee_kernel(const float* __restrict__ eattr,
                                                 const float* __restrict__ Wbe,
                                                 const float* __restrict__ bbe,
                                                 float* __restrict__ ee) {
  __shared__ float Ws[16 * HH];
  __shared__ float Ea[16 * 16];
  int tid = threadIdx.x;
  int e0 = blockIdx.x * 16;
#pragma unroll
  for (int i = 0; i < 8; ++i) Ws[tid + i * 256] = Wbe[tid + i * 256];
  Ea[tid] = eattr[(size_t)e0 * 16 + tid];
  __syncthreads();
  int h = tid & 127, half = tid >> 7;
  float bb = bbe[h];
#pragma unroll
  for (int j = 0; j < 8; ++j) {
    int el = j * 2 + half;
    float acc = bb;
#pragma unroll
    for (int d = 0; d < 16; ++d) acc += Ea[el * 16 + d] * Ws[d * HH + h];
    ee[(size_t)(e0 + el) * HH + h] = acc;
  }
}

// ---- message aggregation: one wave per node; half-waves process alternate edges ---
// Lanes 0-31 take even edges, 32-63 odd edges (float4/lane = 128 cols per half);
// combine via __shfl_xor(...,32). Doubles memory-level parallelism vs r5.
__global__ __launch_bounds__(256) void agg_kernel(const float* __restrict__ x,
                                                  const float* __restrict__ ee,
                                                  const float* __restrict__ emask,
                                                  const int* __restrict__ src,
                                                  const int* __restrict__ off,
                                                  const int* __restrict__ csr_e,
                                                  const float* __restrict__ epsp, int layer,
                                                  float* __restrict__ hout) {
  int wv = threadIdx.x >> 6, lane = threadIdx.x & 63;
  int v = blockIdx.x * 4 + wv;
  int half = lane >> 5, l32 = lane & 31;
  int c4 = l32 * 4;
  float4 acc[CC];
#pragma unroll
  for (int c = 0; c < CC; ++c) { acc[c].x = 0.f; acc[c].y = 0.f; acc[c].z = 0.f; acc[c].w = 0.f; }
  int beg = off[v], end = off[v + 1];
  int t0 = beg + half;
  int e = 0, s = 0;
  if (t0 < end) { e = csr_e[t0]; s = src[e]; }
  for (int t = t0; t < end; t += 2) {
    int tn = t + 2;
    int e2 = 0, s2 = 0;
    if (tn < end) { e2 = csr_e[tn]; s2 = src[e2]; }
    float4 ev = *(const float4*)(ee + (size_t)e * HH + c4);
#pragma unroll
    for (int c = 0; c < CC; ++c) {
      float em = emask[c * EN + e];
      float4 xv = *(const float4*)(x + ((size_t)c * NN + s) * HH + c4);
      acc[c].x += gelu_f(xv.x + ev.x) * em;
      acc[c].y += gelu_f(xv.y + ev.y) * em;
      acc[c].z += gelu_f(xv.z + ev.z) * em;
      acc[c].w += gelu_f(xv.w + ev.w) * em;
    }
    e = e2; s = s2;
  }
  // combine halves
#pragma unroll
  for (int c = 0; c < CC; ++c) {
    acc[c].x += __shfl_xor(acc[c].x, 32);
    acc[c].y += __shfl_xor(acc[c].y, 32);
    acc[c].z += __shfl_xor(acc[c].z, 32);
    acc[c].w += __shfl_xor(acc[c].w, 32);
  }
  float ep = 1.0f + epsp[layer];
  // half 0 writes c=0,1; half 1 writes c=2,3 (full 128 cols each)
#pragma unroll
  for (int cc = 0; cc < 2; ++cc) {
    int c = half * 2 + cc;
    float4 xs = *(const float4*)(x + ((size_t)c * NN + v) * HH + c4);
    float4 o;
    o.x = fmaf(ep, xs.x, acc[c].x);
    o.y = fmaf(ep, xs.y, acc[c].y);
    o.z = fmaf(ep, xs.z, acc[c].z);
    o.w = fmaf(ep, xs.w, acc[c].w);
    *(float4*)(hout + ((size_t)c * NN + v) * HH + c4) = o;
  }
}

// ---- barrier-free MLP: each wave owns a 16-row band end-to-end ----
// A-frags converted straight into registers; B-frags streamed from L2-hot planes;
// t transposed through a PRIVATE per-wave LDS slice (no __syncthreads anywhere).
__global__ __launch_bounds__(256, 3) void mlp_fast_kernel(
    const float* __restrict__ in,
    const unsigned short* __restrict__ w1hi, const unsigned short* __restrict__ w1lo,
    const float* __restrict__ b1,
    const unsigned short* __restrict__ w2hi, const unsigned short* __restrict__ w2lo,
    const float* __restrict__ b2,
    float* __restrict__ out) {
  __shared__ __align__(16) unsigned short T[4][2][16 * LDSA];  // [wave][hi/lo][16 rows]
  int tid = threadIdx.x;
  int lane = tid & 63, wv = tid >> 6;
  int ln = lane & 15, quad = lane >> 4;
  int row0 = blockIdx.x * 64 + wv * 16;  // wave's private 16-row band
  unsigned short* Thi = &T[wv][0][0];
  unsigned short* Tlo = &T[wv][1][0];

  // stage A into registers: lane covers row (row0+ln), cols ks*32+quad*8..+8
  bs8 ahi[4], alo[4];
#pragma unroll
  for (int ks = 0; ks < 4; ++ks) {
    const float* p = in + (size_t)(row0 + ln) * HH + ks * 32 + quad * 8;
    float4 v0 = *(const float4*)p;
    float4 v1 = *(const float4*)(p + 4);
    bs8 h, l;
    h[0] = f2bf(v0.x); h[1] = f2bf(v0.y); h[2] = f2bf(v0.z); h[3] = f2bf(v0.w);
    h[4] = f2bf(v1.x); h[5] = f2bf(v1.y); h[6] = f2bf(v1.z); h[7] = f2bf(v1.w);
    l[0] = f2bf(v0.x - bf2f(h[0])); l[1] = f2bf(v0.y - bf2f(h[1]));
    l[2] = f2bf(v0.z - bf2f(h[2])); l[3] = f2bf(v0.w - bf2f(h[3]));
    l[4] = f2bf(v1.x - bf2f(h[4])); l[5] = f2bf(v1.y - bf2f(h[5]));
    l[6] = f2bf(v1.z - bf2f(h[6])); l[7] = f2bf(v1.w - bf2f(h[7]));
    ahi[ks] = h; alo[ks] = l;
  }

  // GEMM1: 8 col-tiles x 4 k-tiles, 3-term split; B streamed from global (L2-hot)
  f32x4 acc[8];
#pragma unroll
  for (int nt = 0; nt < 8; ++nt)
#pragma unroll
    for (int r = 0; r < 4; ++r) acc[nt][r] = 0.f;
#pragma unroll
  for (int nt = 0; nt < 8; ++nt)
#pragma unroll
    for (int ks = 0; ks < 4; ++ks) {
      int wrow = (nt * 16 + ln) * HH + ks * 32 + quad * 8;
      bs8 bh = *(const bs8*)(w1hi + wrow);
      bs8 bl = *(const bs8*)(w1lo + wrow);
      acc[nt] = __builtin_amdgcn_mfma_f32_16x16x32_bf16(alo[ks], bh, acc[nt], 0, 0, 0);
      acc[nt] = __builtin_amdgcn_mfma_f32_16x16x32_bf16(ahi[ks], bl, acc[nt], 0, 0, 0);
      acc[nt] = __builtin_amdgcn_mfma_f32_16x16x32_bf16(ahi[ks], bh, acc[nt], 0, 0, 0);
    }

  // t = gelu(acc+b1) -> private LDS slice (C-layout -> [row][col]), then reread as A
#pragma unroll
  for (int nt = 0; nt < 8; ++nt) {
    int col = nt * 16 + ln;
    float bb = b1[col];
#pragma unroll
    for (int r = 0; r < 4; ++r) {
      float tv = gelu_f(acc[nt][r] + bb);
      unsigned short th = f2bf(tv);
      int rr = quad * 4 + r;
      Thi[rr * LDSA + col] = th;
      Tlo[rr * LDSA + col] = f2bf(tv - bf2f(th));
    }
  }
  // intra-wave LDS dependency only; compiler inserts lgkmcnt before these reads
#pragma unroll
  for (int ks = 0; ks < 4; ++ks) {
    ahi[ks] = *(const bs8*)(Thi + ln * LDSA + ks * 32 + quad * 8);
    alo[ks] = *(const bs8*)(Tlo + ln * LDSA + ks * 32 + quad * 8);
  }

  // GEMM2
#pragma unroll
  for (int nt = 0; nt < 8; ++nt)
#pragma unroll
    for (int r = 0; r < 4; ++r) acc[nt][r] = 0.f;
#pragma unroll
  for (int nt = 0; nt < 8; ++nt)
#pragma unroll
    for (int ks = 0; ks < 4; ++ks) {
      int wrow = (nt * 16 + ln) * HH + ks * 32 + quad * 8;
      bs8 bh = *(const bs8*)(w2hi + wrow);
      bs8 bl = *(const bs8*)(w2lo + wrow);
      acc[nt] = __builtin_amdgcn_mfma_f32_16x16x32_bf16(alo[ks], bh, acc[nt], 0, 0, 0);
      acc[nt] = __builtin_amdgcn_mfma_f32_16x16x32_bf16(ahi[ks], bl, acc[nt], 0, 0, 0);
      acc[nt] = __builtin_amdgcn_mfma_f32_16x16x32_bf16(ahi[ks], bh, acc[nt], 0, 0, 0);
    }
  // epilogue: outer gelu
#pragma unroll
  for (int nt = 0; nt < 8; ++nt) {
    int col = nt * 16 + ln;
    float bb = b2[col];
#pragma unroll
    for (int r = 0; r < 4; ++r) {
      float o = gelu_f(acc[nt][r] + bb);
      out[(size_t)(row0 + quad * 4 + r) * HH + col] = o;
    }
  }
}

// ---------------- final MLP + fused masked-sum pooling (r5 block-coupled form) ----
__global__ __launch_bounds__(256, 2) void mlp_pool_kernel(
    const float* __restrict__ in,
    const unsigned short* __restrict__ w1hi, const unsigned short* __restrict__ w1lo,
    const float* __restrict__ b1,
    const unsigned short* __restrict__ w2hi, const unsigned short* __restrict__ w2lo,
    const float* __restrict__ b2,
    const float* __restrict__ nmask, const int* __restrict__ batch,
    float* __restrict__ num) {
  __shared__ __align__(16) unsigned short AB[128 * LDSA];  // hi rows 0..63, lo rows 64..127
  __shared__ int kk[64];
  unsigned short* Ahi = AB;
  unsigned short* Alo = AB + 64 * LDSA;
  int tid = threadIdx.x;
  int row0 = blockIdx.x * 64;
  int lane = tid & 63, wq = tid >> 6;
  int ln = lane & 15, quad = lane >> 4;

  bs8 b1h[4][2], b1l[4][2];
#pragma unroll
  for (int ks = 0; ks < 4; ++ks)
#pragma unroll
    for (int nt = 0; nt < 2; ++nt) {
      int wrow = ((wq * 2 + nt) * 16 + ln) * HH + ks * 32 + quad * 8;
      b1h[ks][nt] = *(const bs8*)(w1hi + wrow);
      b1l[ks][nt] = *(const bs8*)(w1lo + wrow);
    }
  // stage A: 64 rows x 128 f32 -> hi/lo bf16
#pragma unroll
  for (int i = 0; i < 8; ++i) {
    int idx = tid + i * 256;
    int r = idx >> 5, cc4 = idx & 31;
    float4 vv = *(const float4*)(in + (size_t)(row0 + r) * HH + cc4 * 4);
    unsigned short h0 = f2bf(vv.x), h1 = f2bf(vv.y), h2 = f2bf(vv.z), h3 = f2bf(vv.w);
    ushort4 hv; hv.x = h0; hv.y = h1; hv.z = h2; hv.w = h3;
    ushort4 lv;
    lv.x = f2bf(vv.x - bf2f(h0)); lv.y = f2bf(vv.y - bf2f(h1));
    lv.z = f2bf(vv.z - bf2f(h2)); lv.w = f2bf(vv.w - bf2f(h3));
    *(ushort4*)(Ahi + r * LDSA + cc4 * 4) = hv;
    *(ushort4*)(Alo + r * LDSA + cc4 * 4) = lv;
  }
  if (tid < 64) {
    int gr = row0 + tid;
    int c = gr / NN;
    int n = gr - c * NN;
    kk[tid] = (c << 6) | batch[n];
  }
  __syncthreads();  // B1

  f32x4 acc[4][2];
#pragma unroll
  for (int mt = 0; mt < 4; ++mt)
#pragma unroll
    for (int nt = 0; nt < 2; ++nt)
#pragma unroll
      for (int r = 0; r < 4; ++r) acc[mt][nt][r] = 0.f;
#pragma unroll
  for (int ks = 0; ks < 4; ++ks) {
    bs8 ah[4], al[4];
#pragma unroll
    for (int mt = 0; mt < 4; ++mt) {
      ah[mt] = *(const bs8*)(Ahi + (mt * 16 + ln) * LDSA + ks * 32 + quad * 8);
      al[mt] = *(const bs8*)(Alo + (mt * 16 + ln) * LDSA + ks * 32 + quad * 8);
    }
#pragma unroll
    for (int nt = 0; nt < 2; ++nt)
#pragma unroll
      for (int mt = 0; mt < 4; ++mt) {
        acc[mt][nt] = __builtin_amdgcn_mfma_f32_16x16x32_bf16(al[mt], b1h[ks][nt], acc[mt][nt], 0, 0, 0);
        acc[mt][nt] = __builtin_amdgcn_mfma_f32_16x16x32_bf16(ah[mt], b1l[ks][nt], acc[mt][nt], 0, 0, 0);
        acc[mt][nt] = __builtin_amdgcn_mfma_f32_16x16x32_bf16(ah[mt], b1h[ks][nt], acc[mt][nt], 0, 0, 0);
      }
  }
  __syncthreads();  // B2

  bs8 b2h[4][2], b2l[4][2];
#pragma unroll
  for (int ks = 0; ks < 4; ++ks)
#pragma unroll
    for (int nt = 0; nt < 2; ++nt) {
      int wrow = ((wq * 2 + nt) * 16 + ln) * HH + ks * 32 + quad * 8;
      b2h[ks][nt] = *(const bs8*)(w2hi + wrow);
      b2l[ks][nt] = *(const bs8*)(w2lo + wrow);
    }
#pragma unroll
  for (int nt = 0; nt < 2; ++nt) {
    int col = (wq * 2 + nt) * 16 + ln;
    float bb = b1[col];
#pragma unroll
    for (int mt = 0; mt < 4; ++mt)
#pragma unroll
      for (int r = 0; r < 4; ++r) {
        float tv = gelu_f(acc[mt][nt][r] + bb);
        unsigned short th = f2bf(tv);
        int rr = mt * 16 + quad * 4 + r;
        Ahi[rr * LDSA + col] = th;
        Alo[rr * LDSA + col] = f2bf(tv - bf2f(th));
      }
  }
  __syncthreads();  // B3

#pragma unroll
  for (int mt = 0; mt < 4; ++mt)
#pragma unroll
    for (int nt = 0; nt < 2; ++nt)
#pragma unroll
      for (int r = 0; r < 4; ++r) acc[mt][nt][r] = 0.f;
#pragma unroll
  for (int ks = 0; ks < 4; ++ks) {
    bs8 ah[4], al[4];
#pragma unroll
    for (int mt = 0; mt < 4; ++mt) {
      ah[mt] = *(const bs8*)(Ahi + (mt * 16 + ln) * LDSA + ks * 32 + quad * 8);
      al[mt] = *(const bs8*)(Alo + (mt * 16 + ln) * LDSA + ks * 32 + quad * 8);
    }
#pragma unroll
    for (int nt = 0; nt < 2; ++nt)
#pragma unroll
      for (int mt = 0; mt < 4; ++mt) {
        acc[mt][nt] = __builtin_amdgcn_mfma_f32_16x16x32_bf16(al[mt], b2h[ks][nt], acc[mt][nt], 0, 0, 0);
        acc[mt][nt] = __builtin_amdgcn_mfma_f32_16x16x32_bf16(ah[mt], b2l[ks][nt], acc[mt][nt], 0, 0, 0);
        acc[mt][nt] = __builtin_amdgcn_mfma_f32_16x16x32_bf16(ah[mt], b2h[ks][nt], acc[mt][nt], 0, 0, 0);
      }
  }
  __syncthreads();  // B4: GEMM2 LDS reads done; LDS reusable for Tf
  float* Tf = (float*)AB;
#pragma unroll
  for (int nt = 0; nt < 2; ++nt) {
    int col = (wq * 2 + nt) * 16 + ln;
    float bb = b2[col];
#pragma unroll
    for (int mt = 0; mt < 4; ++mt)
#pragma unroll
      for (int r = 0; r < 4; ++r) {
        int rl = mt * 16 + quad * 4 + r;
        int gr = row0 + rl;
        Tf[rl * LDSF + col] = (acc[mt][nt][r] + bb) * nmask[gr];
      }
  }
  __syncthreads();  // B5
  if (tid < 128) {
    int col = tid;
    float a2 = 0.f;
    int cur = kk[0];
    for (int r = 0; r < 64; ++r) {
      int k2 = kk[r];
      if (k2 != cur) {
        atomicAdd(&num[((size_t)(cur & 63) * CC + (cur >> 6)) * HH + col], a2);
        a2 = 0.f;
        cur = k2;
      }
      a2 += Tf[r * LDSF + col];
    }
    atomicAdd(&num[((size_t)(cur & 63) * CC + (cur >> 6)) * HH + col], a2);
  }
}

// ---------------- pool finalize: per-(g,c) den reduce (no atomics) + divide -------
__global__ __launch_bounds__(256) void pool_finalize_kernel(const float* __restrict__ num,
                                                            const int* __restrict__ batch,
                                                            const float* __restrict__ nmask,
                                                            float* __restrict__ outp) {
  int g = blockIdx.x >> 2, c = blockIdx.x & 3;
  int lo = 0, hi = NN;
  while (lo < hi) { int m = (lo + hi) >> 1; if (batch[m] < g) lo = m + 1; else hi = m; }
  int start = lo;
  hi = NN;
  while (lo < hi) { int m = (lo + hi) >> 1; if (batch[m] < g + 1) lo = m + 1; else hi = m; }
  int end = lo;
  int tid = threadIdx.x;
  float d = 0.f;
  for (int n = start + tid; n < end; n += 256) d += nmask[c * NN + n];
#pragma unroll
  for (int k = 1; k < 64; k <<= 1) d += __shfl_xor(d, k);
  __shared__ float ws4[4];
  if ((tid & 63) == 0) ws4[tid >> 6] = d;
  __syncthreads();
  float den = ws4[0] + ws4[1] + ws4[2] + ws4[3] + 1e-7f;
  if (tid < 128) {
    int idx = blockIdx.x * 128 + tid;  // (g*4+c)*128 + col — matches output layout
    outp[idx] = num[idx] / den;
  }
}

extern "C" void kernel_launch(void* const* d_in, const int* in_sizes, int n_in,
                              void* d_out, int out_size, void* d_ws, size_t ws_size,
                              hipStream_t stream) {
  const float* x_in  = (const float*)d_in[0];
  const int*   batch = (const int*)d_in[1];
  const int*   eidx  = (const int*)d_in[2];
  const float* eattr = (const float*)d_in[3];
  const float* nmask = (const float*)d_in[4];
  const float* emask = (const float*)d_in[5];
  const float* Wbe   = (const float*)d_in[6];
  const float* bbe   = (const float*)d_in[7];
  const float* epsp  = (const float*)d_in[8];
  const float* W1    = (const float*)d_in[9];
  const float* b1    = (const float*)d_in[10];
  const float* W2    = (const float*)d_in[11];
  const float* b2    = (const float*)d_in[12];
  const float* Wm1   = (const float*)d_in[13];
  const float* bm1   = (const float*)d_in[14];
  const float* Wm2   = (const float*)d_in[15];
  const float* bm2   = (const float*)d_in[16];
  float* outp = (float*)d_out;

  const int* srcp = eidx;
  const int* dstp = eidx + EN;

  // workspace carve
  char* ws = (char*)d_ws;
  float* ee   = (float*)(ws);                  // 102,400,000 B
  float* hbuf = (float*)(ws + 102400000);
  float* xbuf = (float*)(ws + 204800000);
  int* counts  = (int*)(ws + 307200000);       // N
  int* offsets = counts + NN;                  // N+1
  int* cursor  = offsets + NN + 1;             // N
  int* csr_e   = cursor + NN;                  // E
  unsigned short* wts = (unsigned short*)(ws + 307200000 + 1400016);  // 12*16384 bf16
  // temporal overlays in the ee region:
  int* bsums = (int*)ws;                 // before ee_kernel writes ee
  int* boffs = (int*)(ws + 1024);
  float* num = (float*)ws;               // after last ee read (post layer-1 agg)

  const int NB = (NN + 255) / 256;  // 196

  // CSR build
  hipMemsetAsync(counts, 0, NN * sizeof(int), stream);
  count_kernel<<<(EN + 255) / 256, 256, 0, stream>>>(dstp, counts);
  block_sum_kernel<<<NB, 256, 0, stream>>>(counts, bsums);
  bsum_scan_kernel<<<1, 256, 0, stream>>>(bsums, boffs, NB);
  block_scan_kernel<<<NB, 256, 0, stream>>>(counts, boffs, offsets, cursor);
  fill_kernel<<<(EN + 255) / 256, 256, 0, stream>>>(dstp, cursor, csr_e);

  // weight prep (6 matrices in one launch)
  prep_w_kernel<<<384, 256, 0, stream>>>(W1, W2, Wm1, Wm2, wts);

  // bond encoder (overwrites bsums/boffs overlay — stream-ordered after scan)
  ee_kernel<<<EN / 16, 256, 0, stream>>>(eattr, Wbe, bbe, ee);

  // layer 0
  agg_kernel<<<NN / 4, 256, 0, stream>>>(x_in, ee, emask, srcp, offsets, csr_e, epsp, 0, hbuf);
  mlp_fast_kernel<<<(CC * NN) / 64, 256, 0, stream>>>(hbuf, wts + 0, wts + 16384, b1,
                                                      wts + 65536, wts + 81920, b2, xbuf);
  // layer 1
  agg_kernel<<<NN / 4, 256, 0, stream>>>(xbuf, ee, emask, srcp, offsets, csr_e, epsp, 1, hbuf);
  mlp_fast_kernel<<<(CC * NN) / 64, 256, 0, stream>>>(hbuf, wts + 32768, wts + 49152, b1 + 128,
                                                      wts + 98304, wts + 114688, b2 + 128, xbuf);
  // final node MLP with fused masked-sum pooling (ee dead -> num overlay live)
  hipMemsetAsync(num, 0, 131072, stream);
  mlp_pool_kernel<<<(CC * NN) / 64, 256, 0, stream>>>(xbuf, wts + 131072, wts + 147456, bm1,
                                                      wts + 163840, wts + 180224, bm2,
                                                      nmask, batch, num);
  // per-(g,c) denominator reduce + divide (no global atomics)
  pool_finalize_kernel<<<GG * CC, 256, 0, stream>>>(num, batch, nmask, outp);
}

// Round 8
// 739.367 us; speedup vs baseline: 1.3292x; 1.3292x over previous
//
#include <hip/hip_runtime.h>
#include <math.h>

#define NN 50000
#define EN 200000
#define CC 4
#define HH 128
#define GG 64
#define LDSA 136  // padded stride for pool-variant tile
#define LDSF 132  // f32 stride for fused-pool tile

typedef __attribute__((ext_vector_type(8))) short bs8;
typedef __attribute__((ext_vector_type(4))) float f32x4;

__device__ __forceinline__ unsigned short f2bf(float f) {
  unsigned int u = __float_as_uint(f);
  u += 0x7FFFu + ((u >> 16) & 1u);
  return (unsigned short)(u >> 16);
}
__device__ __forceinline__ float bf2f(unsigned short h) {
  return __uint_as_float(((unsigned int)h) << 16);
}
// fast erf-GELU: A&S 7.1.26 minimax (|erf err| ~1.5e-7) + hw rcp/exp
__device__ __forceinline__ float gelu_f(float x) {
  float z = fabsf(x) * 0.7071067811865476f;
  float t = __builtin_amdgcn_rcpf(fmaf(0.3275911f, z, 1.0f));
  float poly = t * fmaf(t, fmaf(t, fmaf(t, fmaf(t, 1.061405429f, -1.453152027f),
                                        1.421413741f), -0.284496736f), 0.254829592f);
  float e = fmaf(-poly, __expf(-z * z), 1.0f);
  return 0.5f * x * (1.0f + copysignf(e, x));
}

// ---------------- CSR build ----------------
__global__ __launch_bounds__(256) void count_kernel(const int* __restrict__ dst,
                                                    int* __restrict__ counts) {
  int e = blockIdx.x * 256 + threadIdx.x;
  if (e < EN) atomicAdd(&counts[dst[e]], 1);
}

__global__ __launch_bounds__(256) void block_sum_kernel(const int* __restrict__ counts,
                                                        int* __restrict__ bsums) {
  int tid = threadIdx.x;
  int i = blockIdx.x * 256 + tid;
  int v = (i < NN) ? counts[i] : 0;
#pragma unroll
  for (int d = 1; d < 64; d <<= 1) v += __shfl_xor(v, d);
  __shared__ int ws4[4];
  if ((tid & 63) == 0) ws4[tid >> 6] = v;
  __syncthreads();
  if (tid == 0) bsums[blockIdx.x] = ws4[0] + ws4[1] + ws4[2] + ws4[3];
}

__global__ __launch_bounds__(256) void bsum_scan_kernel(const int* __restrict__ bsums,
                                                        int* __restrict__ boffs, int nb) {
  int tid = threadIdx.x, lane = tid & 63, wv = tid >> 6;
  int v = (tid < nb) ? bsums[tid] : 0;
  int s = v;
#pragma unroll
  for (int d = 1; d < 64; d <<= 1) { int t = __shfl_up(s, d); if (lane >= d) s += t; }
  __shared__ int wsum[4];
  if (lane == 63) wsum[wv] = s;
  __syncthreads();
  int pre = 0;
  for (int j = 0; j < wv; ++j) pre += wsum[j];
  if (tid < nb) boffs[tid] = pre + s - v;
}

__global__ __launch_bounds__(256) void block_scan_kernel(const int* __restrict__ counts,
                                                         const int* __restrict__ boffs,
                                                         int* __restrict__ offsets,
                                                         int* __restrict__ cursor) {
  int tid = threadIdx.x, lane = tid & 63, wv = tid >> 6;
  int i = blockIdx.x * 256 + tid;
  int v = (i < NN) ? counts[i] : 0;
  int s = v;
#pragma unroll
  for (int d = 1; d < 64; d <<= 1) { int t = __shfl_up(s, d); if (lane >= d) s += t; }
  __shared__ int wsum[4];
  if (lane == 63) wsum[wv] = s;
  __syncthreads();
  int pre = boffs[blockIdx.x];
  for (int j = 0; j < wv; ++j) pre += wsum[j];
  if (i < NN) { int e = pre + s - v; offsets[i] = e; cursor[i] = e; }
  if (i == 0) offsets[NN] = EN;
}

__global__ __launch_bounds__(256) void fill_kernel(const int* __restrict__ dst,
                                                   int* __restrict__ cursor,
                                                   int* __restrict__ csr_e) {
  int e = blockIdx.x * 256 + threadIdx.x;
  if (e < EN) {
    int pos = atomicAdd(&cursor[dst[e]], 1);
    csr_e[pos] = e;
  }
}

// ---------------- weight prep: transpose + hi/lo bf16 split (all 6 matrices) ------
__global__ __launch_bounds__(256) void prep_w_kernel(const float* __restrict__ W1,
                                                     const float* __restrict__ W2,
                                                     const float* __restrict__ Wm1,
                                                     const float* __restrict__ Wm2,
                                                     unsigned short* __restrict__ wts) {
  int m = blockIdx.x >> 6;
  int idx = (blockIdx.x & 63) * 256 + threadIdx.x;  // 0..16383
  const float* src = (m == 0) ? W1 : (m == 1) ? W1 + 16384 : (m == 2) ? W2
                     : (m == 3) ? W2 + 16384 : (m == 4) ? Wm1 : Wm2;
  unsigned short* dhi = wts + m * 32768;
  unsigned short* dlo = dhi + 16384;
  int n = idx >> 7, k = idx & 127;
  float v = src[k * HH + n];  // src [k][n] -> dst [n][k]
  unsigned short hi = f2bf(v);
  dhi[n * HH + k] = hi;
  dlo[n * HH + k] = f2bf(v - bf2f(hi));
}

// ---------------- bond encoder: 16 edges per block ----------------
__global__ __launch_bounds__(256) void ee_kernel(const float* __restrict__ eattr,
                                                 const float* __restrict__ Wbe,
                                                 const float* __restrict__ bbe,
                                                 float* __restrict__ ee) {
  __shared__ float Ws[16 * HH];
  __shared__ float Ea[16 * 16];
  int tid = threadIdx.x;
  int e0 = blockIdx.x * 16;
#pragma unroll
  for (int i = 0; i < 8; ++i) Ws[tid + i * 256] = Wbe[tid + i * 256];
  Ea[tid] = eattr[(size_t)e0 * 16 + tid];
  __syncthreads();
  int h = tid & 127, half = tid >> 7;
  float bb = bbe[h];
#pragma unroll
  for (int j = 0; j < 8; ++j) {
    int el = j * 2 + half;
    float acc = bb;
#pragma unroll
    for (int d = 0; d < 16; ++d) acc += Ea[el * 16 + d] * Ws[d * HH + h];
    ee[(size_t)(e0 + el) * HH + h] = acc;
  }
}

// ---- message aggregation: one wave per node; half-waves process alternate edges ---
__global__ __launch_bounds__(256) void agg_kernel(const float* __restrict__ x,
                                                  const float* __restrict__ ee,
                                                  const float* __restrict__ emask,
                                                  const int* __restrict__ src,
                                                  const int* __restrict__ off,
                                                  const int* __restrict__ csr_e,
                                                  const float* __restrict__ epsp, int layer,
                                                  float* __restrict__ hout) {
  int wv = threadIdx.x >> 6, lane = threadIdx.x & 63;
  int v = blockIdx.x * 4 + wv;
  int half = lane >> 5, l32 = lane & 31;
  int c4 = l32 * 4;
  float4 acc[CC];
#pragma unroll
  for (int c = 0; c < CC; ++c) { acc[c].x = 0.f; acc[c].y = 0.f; acc[c].z = 0.f; acc[c].w = 0.f; }
  int beg = off[v], end = off[v + 1];
  int t0 = beg + half;
  int e = 0, s = 0;
  if (t0 < end) { e = csr_e[t0]; s = src[e]; }
  for (int t = t0; t < end; t += 2) {
    int tn = t + 2;
    int e2 = 0, s2 = 0;
    if (tn < end) { e2 = csr_e[tn]; s2 = src[e2]; }
    float4 ev = *(const float4*)(ee + (size_t)e * HH + c4);
#pragma unroll
    for (int c = 0; c < CC; ++c) {
      float em = emask[c * EN + e];
      float4 xv = *(const float4*)(x + ((size_t)c * NN + s) * HH + c4);
      acc[c].x += gelu_f(xv.x + ev.x) * em;
      acc[c].y += gelu_f(xv.y + ev.y) * em;
      acc[c].z += gelu_f(xv.z + ev.z) * em;
      acc[c].w += gelu_f(xv.w + ev.w) * em;
    }
    e = e2; s = s2;
  }
#pragma unroll
  for (int c = 0; c < CC; ++c) {
    acc[c].x += __shfl_xor(acc[c].x, 32);
    acc[c].y += __shfl_xor(acc[c].y, 32);
    acc[c].z += __shfl_xor(acc[c].z, 32);
    acc[c].w += __shfl_xor(acc[c].w, 32);
  }
  float ep = 1.0f + epsp[layer];
#pragma unroll
  for (int cc = 0; cc < 2; ++cc) {
    int c = half * 2 + cc;
    float4 xs = *(const float4*)(x + ((size_t)c * NN + v) * HH + c4);
    float4 o;
    o.x = fmaf(ep, xs.x, acc[c].x);
    o.y = fmaf(ep, xs.y, acc[c].y);
    o.z = fmaf(ep, xs.z, acc[c].z);
    o.w = fmaf(ep, xs.w, acc[c].w);
    *(float4*)(hout + ((size_t)c * NN + v) * HH + c4) = o;
  }
}

// ---------------- MLP (mode-0), 64 rows/block, XOR-swizzled 32 KB LDS -------------
// stored 16B-block index = logical_block ^ (row & 15) -> exact 32768 B (5 blocks/CU),
// all wave64 LDS ops <=2-way banked. B-frags preloaded as named arrays (in-flight).
__global__ __launch_bounds__(256, 2) void mlp_kernel(
    const float* __restrict__ in,
    const unsigned short* __restrict__ w1hi, const unsigned short* __restrict__ w1lo,
    const float* __restrict__ b1,
    const unsigned short* __restrict__ w2hi, const unsigned short* __restrict__ w2lo,
    const float* __restrict__ b2,
    float* __restrict__ out) {
  __shared__ __align__(16) unsigned short AB[2 * 64 * HH];  // hi plane, lo plane
  unsigned short* Ahi = AB;
  unsigned short* Alo = AB + 64 * HH;
  int tid = threadIdx.x;
  int row0 = blockIdx.x * 64;
  int lane = tid & 63, wq = tid >> 6;
  int ln = lane & 15, quad = lane >> 4;

  // Preload GEMM1 B-fragments (latency overlaps stage-A + barrier)
  bs8 b1h[4][2], b1l[4][2];
#pragma unroll
  for (int ks = 0; ks < 4; ++ks)
#pragma unroll
    for (int nt = 0; nt < 2; ++nt) {
      int wrow = ((wq * 2 + nt) * 16 + ln) * HH + ks * 32 + quad * 8;
      b1h[ks][nt] = *(const bs8*)(w1hi + wrow);
      b1l[ks][nt] = *(const bs8*)(w1lo + wrow);
    }

  // stage A: 1024 16B-blocks per plane, swizzled
#pragma unroll
  for (int i = 0; i < 4; ++i) {
    int idx = tid + i * 256;       // 0..1023
    int r = idx >> 4, blk = idx & 15;
    const float* p = in + (size_t)(row0 + r) * HH + blk * 8;
    float4 v0 = *(const float4*)p;
    float4 v1 = *(const float4*)(p + 4);
    bs8 h, l;
    h[0] = f2bf(v0.x); h[1] = f2bf(v0.y); h[2] = f2bf(v0.z); h[3] = f2bf(v0.w);
    h[4] = f2bf(v1.x); h[5] = f2bf(v1.y); h[6] = f2bf(v1.z); h[7] = f2bf(v1.w);
    l[0] = f2bf(v0.x - bf2f(h[0])); l[1] = f2bf(v0.y - bf2f(h[1]));
    l[2] = f2bf(v0.z - bf2f(h[2])); l[3] = f2bf(v0.w - bf2f(h[3]));
    l[4] = f2bf(v1.x - bf2f(h[4])); l[5] = f2bf(v1.y - bf2f(h[5]));
    l[6] = f2bf(v1.z - bf2f(h[6])); l[7] = f2bf(v1.w - bf2f(h[7]));
    int sb = blk ^ (r & 15);
    *(bs8*)(Ahi + r * HH + sb * 8) = h;
    *(bs8*)(Alo + r * HH + sb * 8) = l;
  }
  __syncthreads();  // B1: A staged

  f32x4 acc[4][2];
#pragma unroll
  for (int mt = 0; mt < 4; ++mt)
#pragma unroll
    for (int nt = 0; nt < 2; ++nt)
#pragma unroll
      for (int r = 0; r < 4; ++r) acc[mt][nt][r] = 0.f;
  // GEMM1 (3-term split)
#pragma unroll
  for (int ks = 0; ks < 4; ++ks) {
    bs8 ah[4], al[4];
    int sb = ((ks * 4 + quad) ^ ln) * 8;
#pragma unroll
    for (int mt = 0; mt < 4; ++mt) {
      ah[mt] = *(const bs8*)(Ahi + (mt * 16 + ln) * HH + sb);
      al[mt] = *(const bs8*)(Alo + (mt * 16 + ln) * HH + sb);
    }
#pragma unroll
    for (int nt = 0; nt < 2; ++nt)
#pragma unroll
      for (int mt = 0; mt < 4; ++mt) {
        acc[mt][nt] = __builtin_amdgcn_mfma_f32_16x16x32_bf16(al[mt], b1h[ks][nt], acc[mt][nt], 0, 0, 0);
        acc[mt][nt] = __builtin_amdgcn_mfma_f32_16x16x32_bf16(ah[mt], b1l[ks][nt], acc[mt][nt], 0, 0, 0);
        acc[mt][nt] = __builtin_amdgcn_mfma_f32_16x16x32_bf16(ah[mt], b1h[ks][nt], acc[mt][nt], 0, 0, 0);
      }
  }
  __syncthreads();  // B2: GEMM1 LDS reads done

  // Preload GEMM2 B-fragments (hidden under t-stage + barrier)
  bs8 b2h[4][2], b2l[4][2];
#pragma unroll
  for (int ks = 0; ks < 4; ++ks)
#pragma unroll
    for (int nt = 0; nt < 2; ++nt) {
      int wrow = ((wq * 2 + nt) * 16 + ln) * HH + ks * 32 + quad * 8;
      b2h[ks][nt] = *(const bs8*)(w2hi + wrow);
      b2l[ks][nt] = *(const bs8*)(w2lo + wrow);
    }

  // t = gelu(acc + b1) -> swizzled LDS hi/lo
#pragma unroll
  for (int nt = 0; nt < 2; ++nt) {
    int col = (wq * 2 + nt) * 16 + ln;
    int cb = col >> 3, co = col & 7;
    float bb = b1[col];
#pragma unroll
    for (int mt = 0; mt < 4; ++mt)
#pragma unroll
      for (int r = 0; r < 4; ++r) {
        float tv = gelu_f(acc[mt][nt][r] + bb);
        unsigned short th = f2bf(tv);
        int rr = mt * 16 + quad * 4 + r;
        int sof = rr * HH + (cb ^ (rr & 15)) * 8 + co;
        Ahi[sof] = th;
        Alo[sof] = f2bf(tv - bf2f(th));
      }
  }
  __syncthreads();  // B3: t staged

#pragma unroll
  for (int mt = 0; mt < 4; ++mt)
#pragma unroll
    for (int nt = 0; nt < 2; ++nt)
#pragma unroll
      for (int r = 0; r < 4; ++r) acc[mt][nt][r] = 0.f;
  // GEMM2
#pragma unroll
  for (int ks = 0; ks < 4; ++ks) {
    bs8 ah[4], al[4];
    int sb = ((ks * 4 + quad) ^ ln) * 8;
#pragma unroll
    for (int mt = 0; mt < 4; ++mt) {
      ah[mt] = *(const bs8*)(Ahi + (mt * 16 + ln) * HH + sb);
      al[mt] = *(const bs8*)(Alo + (mt * 16 + ln) * HH + sb);
    }
#pragma unroll
    for (int nt = 0; nt < 2; ++nt)
#pragma unroll
      for (int mt = 0; mt < 4; ++mt) {
        acc[mt][nt] = __builtin_amdgcn_mfma_f32_16x16x32_bf16(al[mt], b2h[ks][nt], acc[mt][nt], 0, 0, 0);
        acc[mt][nt] = __builtin_amdgcn_mfma_f32_16x16x32_bf16(ah[mt], b2l[ks][nt], acc[mt][nt], 0, 0, 0);
        acc[mt][nt] = __builtin_amdgcn_mfma_f32_16x16x32_bf16(ah[mt], b2h[ks][nt], acc[mt][nt], 0, 0, 0);
      }
  }
  // epilogue: outer gelu
#pragma unroll
  for (int nt = 0; nt < 2; ++nt) {
    int col = (wq * 2 + nt) * 16 + ln;
    float bb = b2[col];
#pragma unroll
    for (int mt = 0; mt < 4; ++mt)
#pragma unroll
      for (int r = 0; r < 4; ++r) {
        float o = gelu_f(acc[mt][nt][r] + bb);
        out[(size_t)(row0 + mt * 16 + quad * 4 + r) * HH + col] = o;
      }
  }
}

// ---------------- final MLP + fused masked-sum pooling (r5 padded form) -----------
__global__ __launch_bounds__(256, 2) void mlp_pool_kernel(
    const float* __restrict__ in,
    const unsigned short* __restrict__ w1hi, const unsigned short* __restrict__ w1lo,
    const float* __restrict__ b1,
    const unsigned short* __restrict__ w2hi, const unsigned short* __restrict__ w2lo,
    const float* __restrict__ b2,
    const float* __restrict__ nmask, const int* __restrict__ batch,
    float* __restrict__ num) {
  __shared__ __align__(16) unsigned short AB[128 * LDSA];
  __shared__ int kk[64];
  unsigned short* Ahi = AB;
  unsigned short* Alo = AB + 64 * LDSA;
  int tid = threadIdx.x;
  int row0 = blockIdx.x * 64;
  int lane = tid & 63, wq = tid >> 6;
  int ln = lane & 15, quad = lane >> 4;

  bs8 b1h[4][2], b1l[4][2];
#pragma unroll
  for (int ks = 0; ks < 4; ++ks)
#pragma unroll
    for (int nt = 0; nt < 2; ++nt) {
      int wrow = ((wq * 2 + nt) * 16 + ln) * HH + ks * 32 + quad * 8;
      b1h[ks][nt] = *(const bs8*)(w1hi + wrow);
      b1l[ks][nt] = *(const bs8*)(w1lo + wrow);
    }
#pragma unroll
  for (int i = 0; i < 8; ++i) {
    int idx = tid + i * 256;
    int r = idx >> 5, cc4 = idx & 31;
    float4 vv = *(const float4*)(in + (size_t)(row0 + r) * HH + cc4 * 4);
    unsigned short h0 = f2bf(vv.x), h1 = f2bf(vv.y), h2 = f2bf(vv.z), h3 = f2bf(vv.w);
    ushort4 hv; hv.x = h0; hv.y = h1; hv.z = h2; hv.w = h3;
    ushort4 lv;
    lv.x = f2bf(vv.x - bf2f(h0)); lv.y = f2bf(vv.y - bf2f(h1));
    lv.z = f2bf(vv.z - bf2f(h2)); lv.w = f2bf(vv.w - bf2f(h3));
    *(ushort4*)(Ahi + r * LDSA + cc4 * 4) = hv;
    *(ushort4*)(Alo + r * LDSA + cc4 * 4) = lv;
  }
  if (tid < 64) {
    int gr = row0 + tid;
    int c = gr / NN;
    int n = gr - c * NN;
    kk[tid] = (c << 6) | batch[n];
  }
  __syncthreads();  // B1

  f32x4 acc[4][2];
#pragma unroll
  for (int mt = 0; mt < 4; ++mt)
#pragma unroll
    for (int nt = 0; nt < 2; ++nt)
#pragma unroll
      for (int r = 0; r < 4; ++r) acc[mt][nt][r] = 0.f;
#pragma unroll
  for (int ks = 0; ks < 4; ++ks) {
    bs8 ah[4], al[4];
#pragma unroll
    for (int mt = 0; mt < 4; ++mt) {
      ah[mt] = *(const bs8*)(Ahi + (mt * 16 + ln) * LDSA + ks * 32 + quad * 8);
      al[mt] = *(const bs8*)(Alo + (mt * 16 + ln) * LDSA + ks * 32 + quad * 8);
    }
#pragma unroll
    for (int nt = 0; nt < 2; ++nt)
#pragma unroll
      for (int mt = 0; mt < 4; ++mt) {
        acc[mt][nt] = __builtin_amdgcn_mfma_f32_16x16x32_bf16(al[mt], b1h[ks][nt], acc[mt][nt], 0, 0, 0);
        acc[mt][nt] = __builtin_amdgcn_mfma_f32_16x16x32_bf16(ah[mt], b1l[ks][nt], acc[mt][nt], 0, 0, 0);
        acc[mt][nt] = __builtin_amdgcn_mfma_f32_16x16x32_bf16(ah[mt], b1h[ks][nt], acc[mt][nt], 0, 0, 0);
      }
  }
  __syncthreads();  // B2

  bs8 b2h[4][2], b2l[4][2];
#pragma unroll
  for (int ks = 0; ks < 4; ++ks)
#pragma unroll
    for (int nt = 0; nt < 2; ++nt) {
      int wrow = ((wq * 2 + nt) * 16 + ln) * HH + ks * 32 + quad * 8;
      b2h[ks][nt] = *(const bs8*)(w2hi + wrow);
      b2l[ks][nt] = *(const bs8*)(w2lo + wrow);
    }
#pragma unroll
  for (int nt = 0; nt < 2; ++nt) {
    int col = (wq * 2 + nt) * 16 + ln;
    float bb = b1[col];
#pragma unroll
    for (int mt = 0; mt < 4; ++mt)
#pragma unroll
      for (int r = 0; r < 4; ++r) {
        float tv = gelu_f(acc[mt][nt][r] + bb);
        unsigned short th = f2bf(tv);
        int rr = mt * 16 + quad * 4 + r;
        Ahi[rr * LDSA + col] = th;
        Alo[rr * LDSA + col] = f2bf(tv - bf2f(th));
      }
  }
  __syncthreads();  // B3

#pragma unroll
  for (int mt = 0; mt < 4; ++mt)
#pragma unroll
    for (int nt = 0; nt < 2; ++nt)
#pragma unroll
      for (int r = 0; r < 4; ++r) acc[mt][nt][r] = 0.f;
#pragma unroll
  for (int ks = 0; ks < 4; ++ks) {
    bs8 ah[4], al[4];
#pragma unroll
    for (int mt = 0; mt < 4; ++mt) {
      ah[mt] = *(const bs8*)(Ahi + (mt * 16 + ln) * LDSA + ks * 32 + quad * 8);
      al[mt] = *(const bs8*)(Alo + (mt * 16 + ln) * LDSA + ks * 32 + quad * 8);
    }
#pragma unroll
    for (int nt = 0; nt < 2; ++nt)
#pragma unroll
      for (int mt = 0; mt < 4; ++mt) {
        acc[mt][nt] = __builtin_amdgcn_mfma_f32_16x16x32_bf16(al[mt], b2h[ks][nt], acc[mt][nt], 0, 0, 0);
        acc[mt][nt] = __builtin_amdgcn_mfma_f32_16x16x32_bf16(ah[mt], b2l[ks][nt], acc[mt][nt], 0, 0, 0);
        acc[mt][nt] = __builtin_amdgcn_mfma_f32_16x16x32_bf16(ah[mt], b2h[ks][nt], acc[mt][nt], 0, 0, 0);
      }
  }
  __syncthreads();  // B4
  float* Tf = (float*)AB;
#pragma unroll
  for (int nt = 0; nt < 2; ++nt) {
    int col = (wq * 2 + nt) * 16 + ln;
    float bb = b2[col];
#pragma unroll
    for (int mt = 0; mt < 4; ++mt)
#pragma unroll
      for (int r = 0; r < 4; ++r) {
        int rl = mt * 16 + quad * 4 + r;
        int gr = row0 + rl;
        Tf[rl * LDSF + col] = (acc[mt][nt][r] + bb) * nmask[gr];
      }
  }
  __syncthreads();  // B5
  if (tid < 128) {
    int col = tid;
    float a2 = 0.f;
    int cur = kk[0];
    for (int r = 0; r < 64; ++r) {
      int k2 = kk[r];
      if (k2 != cur) {
        atomicAdd(&num[((size_t)(cur & 63) * CC + (cur >> 6)) * HH + col], a2);
        a2 = 0.f;
        cur = k2;
      }
      a2 += Tf[r * LDSF + col];
    }
    atomicAdd(&num[((size_t)(cur & 63) * CC + (cur >> 6)) * HH + col], a2);
  }
}

// ---------------- pool finalize ----------------
__global__ __launch_bounds__(256) void pool_finalize_kernel(const float* __restrict__ num,
                                                            const int* __restrict__ batch,
                                                            const float* __restrict__ nmask,
                                                            float* __restrict__ outp) {
  int g = blockIdx.x >> 2, c = blockIdx.x & 3;
  int lo = 0, hi = NN;
  while (lo < hi) { int m = (lo + hi) >> 1; if (batch[m] < g) lo = m + 1; else hi = m; }
  int start = lo;
  hi = NN;
  while (lo < hi) { int m = (lo + hi) >> 1; if (batch[m] < g + 1) lo = m + 1; else hi = m; }
  int end = lo;
  int tid = threadIdx.x;
  float d = 0.f;
  for (int n = start + tid; n < end; n += 256) d += nmask[c * NN + n];
#pragma unroll
  for (int k = 1; k < 64; k <<= 1) d += __shfl_xor(d, k);
  __shared__ float ws4[4];
  if ((tid & 63) == 0) ws4[tid >> 6] = d;
  __syncthreads();
  float den = ws4[0] + ws4[1] + ws4[2] + ws4[3] + 1e-7f;
  if (tid < 128) {
    int idx = blockIdx.x * 128 + tid;
    outp[idx] = num[idx] / den;
  }
}

extern "C" void kernel_launch(void* const* d_in, const int* in_sizes, int n_in,
                              void* d_out, int out_size, void* d_ws, size_t ws_size,
                              hipStream_t stream) {
  const float* x_in  = (const float*)d_in[0];
  const int*   batch = (const int*)d_in[1];
  const int*   eidx  = (const int*)d_in[2];
  const float* eattr = (const float*)d_in[3];
  const float* nmask = (const float*)d_in[4];
  const float* emask = (const float*)d_in[5];
  const float* Wbe   = (const float*)d_in[6];
  const float* bbe   = (const float*)d_in[7];
  const float* epsp  = (const float*)d_in[8];
  const float* W1    = (const float*)d_in[9];
  const float* b1    = (const float*)d_in[10];
  const float* W2    = (const float*)d_in[11];
  const float* b2    = (const float*)d_in[12];
  const float* Wm1   = (const float*)d_in[13];
  const float* bm1   = (const float*)d_in[14];
  const float* Wm2   = (const float*)d_in[15];
  const float* bm2   = (const float*)d_in[16];
  float* outp = (float*)d_out;

  const int* srcp = eidx;
  const int* dstp = eidx + EN;

  char* ws = (char*)d_ws;
  float* ee   = (float*)(ws);                  // 102,400,000 B
  float* hbuf = (float*)(ws + 102400000);
  float* xbuf = (float*)(ws + 204800000);
  int* counts  = (int*)(ws + 307200000);       // N
  int* offsets = counts + NN;                  // N+1
  int* cursor  = offsets + NN + 1;             // N
  int* csr_e   = cursor + NN;                  // E
  unsigned short* wts = (unsigned short*)(ws + 307200000 + 1400016);  // 12*16384 bf16
  int* bsums = (int*)ws;                 // overlay: before ee_kernel writes ee
  int* boffs = (int*)(ws + 1024);
  float* num = (float*)ws;               // overlay: after last ee read

  const int NB = (NN + 255) / 256;  // 196

  hipMemsetAsync(counts, 0, NN * sizeof(int), stream);
  count_kernel<<<(EN + 255) / 256, 256, 0, stream>>>(dstp, counts);
  block_sum_kernel<<<NB, 256, 0, stream>>>(counts, bsums);
  bsum_scan_kernel<<<1, 256, 0, stream>>>(bsums, boffs, NB);
  block_scan_kernel<<<NB, 256, 0, stream>>>(counts, boffs, offsets, cursor);
  fill_kernel<<<(EN + 255) / 256, 256, 0, stream>>>(dstp, cursor, csr_e);

  prep_w_kernel<<<384, 256, 0, stream>>>(W1, W2, Wm1, Wm2, wts);

  ee_kernel<<<EN / 16, 256, 0, stream>>>(eattr, Wbe, bbe, ee);

  // layer 0
  agg_kernel<<<NN / 4, 256, 0, stream>>>(x_in, ee, emask, srcp, offsets, csr_e, epsp, 0, hbuf);
  mlp_kernel<<<(CC * NN) / 64, 256, 0, stream>>>(hbuf, wts + 0, wts + 16384, b1,
                                                 wts + 65536, wts + 81920, b2, xbuf);
  // layer 1
  agg_kernel<<<NN / 4, 256, 0, stream>>>(xbuf, ee, emask, srcp, offsets, csr_e, epsp, 1, hbuf);
  mlp_kernel<<<(CC * NN) / 64, 256, 0, stream>>>(hbuf, wts + 32768, wts + 49152, b1 + 128,
                                                 wts + 98304, wts + 114688, b2 + 128, xbuf);
  // final node MLP with fused masked-sum pooling
  hipMemsetAsync(num, 0, 131072, stream);
  mlp_pool_kernel<<<(CC * NN) / 64, 256, 0, stream>>>(xbuf, wts + 131072, wts + 147456, bm1,
                                                      wts + 163840, wts + 180224, bm2,
                                                      nmask, batch, num);
  pool_finalize_kernel<<<GG * CC, 256, 0, stream>>>(num, batch, nmask, outp);
}